// Round 1
// baseline (647.643 us; speedup 1.0000x reference)
//
#include <hip/hip_runtime.h>

typedef unsigned short u16;
typedef short bf16x8 __attribute__((ext_vector_type(8)));
typedef float f32x4 __attribute__((ext_vector_type(4)));

__device__ __forceinline__ u16 f2bf(float f) {
  union { float f; unsigned u; } x; x.f = f;
  unsigned r = x.u + 0x7FFFu + ((x.u >> 16) & 1u);
  return (u16)(r >> 16);
}
__device__ __forceinline__ float bf_lo(unsigned u) {
  union { unsigned u; float f; } x; x.u = u << 16; return x.f;
}
__device__ __forceinline__ float bf_hi(unsigned u) {
  union { unsigned u; float f; } x; x.u = u & 0xFFFF0000u; return x.f;
}
__device__ __forceinline__ unsigned pack2bf(float a, float b) {
  return (unsigned)f2bf(a) | ((unsigned)f2bf(b) << 16);
}

// ---------------------------------------------------------------- weights ---
// out[n*K + k] = bf16(in[k*N + n])   (K x N fp32  ->  N x K bf16)
__global__ void tconv(const float* __restrict__ in, u16* __restrict__ out, int K, int N) {
  int idx = blockIdx.x * 256 + threadIdx.x;
  if (idx >= K * N) return;
  int n = idx / K, k2 = idx - n * K;
  out[idx] = f2bf(in[(size_t)k2 * N + n]);
}

// ------------------------------------------------------- LN1+shift+window ---
__global__ __launch_bounds__(256)
void ln1_win(const float* __restrict__ x1, const float* __restrict__ x2,
             const float* __restrict__ x3, const float* __restrict__ g,
             const float* __restrict__ bb, u16* __restrict__ o1,
             u16* __restrict__ o2, u16* __restrict__ o3) {
  const int t = blockIdx.x * 4 + (threadIdx.x >> 6);
  const int lane = threadIdx.x & 63;
  const int win = t / 49, i = t - win * 49;
  const int b = win >> 6, wi = win & 63;
  const int ih = i / 7, iw = i - ih * 7;
  int h2 = (wi >> 3) * 7 + ih + 3; if (h2 >= 56) h2 -= 56;
  int w2 = (wi & 7) * 7 + iw + 3; if (w2 >= 56) w2 -= 56;
  const size_t src = ((size_t)b * 3136 + (size_t)h2 * 56 + w2) * 256 + lane * 4;
  const size_t dst = (size_t)t * 256 + lane * 4;
  const float4 gv = *(const float4*)(g + lane * 4);
  const float4 bv = *(const float4*)(bb + lane * 4);
  const float* xs[3] = {x1, x2, x3};
  u16* os[3] = {o1, o2, o3};
#pragma unroll
  for (int s = 0; s < 3; ++s) {
    float4 v = *(const float4*)(xs[s] + src);
    float sm = v.x + v.y + v.z + v.w;
    float s2 = v.x * v.x + v.y * v.y + v.z * v.z + v.w * v.w;
#pragma unroll
    for (int off = 32; off > 0; off >>= 1) {
      sm += __shfl_down(sm, off);
      s2 += __shfl_down(s2, off);
    }
    sm = __shfl(sm, 0); s2 = __shfl(s2, 0);
    float mean = sm * (1.f / 256.f);
    float rstd = rsqrtf(s2 * (1.f / 256.f) - mean * mean + 1e-5f);
    ushort4 o;
    o.x = f2bf((v.x - mean) * rstd * gv.x + bv.x);
    o.y = f2bf((v.y - mean) * rstd * gv.y + bv.y);
    o.z = f2bf((v.z - mean) * rstd * gv.z + bv.z);
    o.w = f2bf((v.w - mean) * rstd * gv.w + bv.w);
    *(ushort4*)(os[s] + dst) = o;
  }
}

// ------------------------------------------------------------------- LN2 ----
__global__ __launch_bounds__(256)
void ln2_k(const float* __restrict__ x, const float* __restrict__ g,
           const float* __restrict__ bb, u16* __restrict__ o) {
  const int t = blockIdx.x * 4 + (threadIdx.x >> 6);
  const int lane = threadIdx.x & 63;
  const size_t off = (size_t)t * 256 + lane * 4;
  const float4 gv = *(const float4*)(g + lane * 4);
  const float4 bv = *(const float4*)(bb + lane * 4);
  float4 v = *(const float4*)(x + off);
  float sm = v.x + v.y + v.z + v.w;
  float s2 = v.x * v.x + v.y * v.y + v.z * v.z + v.w * v.w;
#pragma unroll
  for (int d = 32; d > 0; d >>= 1) {
    sm += __shfl_down(sm, d);
    s2 += __shfl_down(s2, d);
  }
  sm = __shfl(sm, 0); s2 = __shfl(s2, 0);
  float mean = sm * (1.f / 256.f);
  float rstd = rsqrtf(s2 * (1.f / 256.f) - mean * mean + 1e-5f);
  ushort4 ov;
  ov.x = f2bf((v.x - mean) * rstd * gv.x + bv.x);
  ov.y = f2bf((v.y - mean) * rstd * gv.y + bv.y);
  ov.z = f2bf((v.z - mean) * rstd * gv.z + bv.z);
  ov.w = f2bf((v.w - mean) * rstd * gv.w + bv.w);
  *(ushort4*)(o + off) = ov;
}

// ------------------------------------------------------------------ GEMM ----
// C = A(MxK bf16) @ Bt^T(NxK bf16) with epilogues:
// EPI 0: out bf16 = alpha*(acc+bias)          (Q/K/V)
// EPI 1: out bf16 = gelu(acc+bias)            (MLP1)
// EPI 2: out fp32 scatter: x_mid = x1 + acc+bias  (proj + win_rev + unshift)
// EPI 3: out fp32 = res + acc+bias            (MLP2 + residual)
#define BM 128
#define BN 128
#define BK 64

template <int EPI>
__global__ __launch_bounds__(256, 2)
void gemm_nt(const u16* __restrict__ A, const u16* __restrict__ Bt,
             const float* __restrict__ bias, float alpha, int M, int N, int K,
             void* __restrict__ out_, const float* __restrict__ res) {
  __shared__ u16 As[2][BM * BK];
  __shared__ u16 Bs[2][BN * BK];
  const int tid = threadIdx.x;
  const int lane = tid & 63;
  const int wave = tid >> 6;
  const int wm = wave >> 1, wn = wave & 1;
  const long tM = (long)blockIdx.x * BM, tN = (long)blockIdx.y * BN;

  f32x4 acc[4][4] = {};

  auto stage = [&](u16* dst, const u16* src, long rowBase, int ld, int kOff) {
#pragma unroll
    for (int it = 0; it < 4; ++it) {
      int gi = it * 256 + tid;
      int row = gi >> 3, gl = gi & 7;
      int gs = gl ^ (row & 7);
      uint4 vv = *(const uint4*)(src + (size_t)(rowBase + row) * ld + kOff + gs * 8);
      *(uint4*)(dst + row * BK + gl * 8) = vv;
    }
  };

  stage(As[0], A, tM, K, 0);
  stage(Bs[0], Bt, tN, K, 0);
  __syncthreads();

  const int nkt = K / BK;
  for (int kt = 0; kt < nkt; ++kt) {
    const int cur = kt & 1;
    if (kt + 1 < nkt) {
      stage(As[cur ^ 1], A, tM, K, (kt + 1) * BK);
      stage(Bs[cur ^ 1], Bt, tN, K, (kt + 1) * BK);
    }
#pragma unroll
    for (int kk = 0; kk < BK; kk += 32) {
      bf16x8 af[4], bfv[4];
#pragma unroll
      for (int m = 0; m < 4; ++m) {
        int row = wm * 64 + m * 16 + (lane & 15);
        int g = (kk >> 3) + (lane >> 4);
        af[m] = *(const bf16x8*)&As[cur][row * BK + ((g ^ (row & 7)) << 3)];
      }
#pragma unroll
      for (int n = 0; n < 4; ++n) {
        int col = wn * 64 + n * 16 + (lane & 15);
        int g = (kk >> 3) + (lane >> 4);
        bfv[n] = *(const bf16x8*)&Bs[cur][col * BK + ((g ^ (col & 7)) << 3)];
      }
#pragma unroll
      for (int m = 0; m < 4; ++m)
#pragma unroll
        for (int n = 0; n < 4; ++n)
          acc[m][n] = __builtin_amdgcn_mfma_f32_16x16x32_bf16(af[m], bfv[n], acc[m][n], 0, 0, 0);
    }
    __syncthreads();
  }

#pragma unroll
  for (int m = 0; m < 4; ++m) {
#pragma unroll
    for (int r = 0; r < 4; ++r) {
      const long row = tM + wm * 64 + m * 16 + (lane >> 4) * 4 + r;
      if constexpr (EPI == 2) {
        int win = (int)(row / 49), i = (int)(row - (long)win * 49);
        int b = win >> 6, wi = win & 63;
        int ih = i / 7, iw = i - ih * 7;
        int h2 = (wi >> 3) * 7 + ih + 3; if (h2 >= 56) h2 -= 56;
        int w2 = (wi & 7) * 7 + iw + 3; if (w2 >= 56) w2 -= 56;
        size_t obase = ((size_t)b * 3136 + (size_t)h2 * 56 + w2) * 256;
        float* out = (float*)out_;
#pragma unroll
        for (int n = 0; n < 4; ++n) {
          int col = (int)tN + wn * 64 + n * 16 + (lane & 15);
          out[obase + col] = res[obase + col] + acc[m][n][r] + bias[col];
        }
      } else if constexpr (EPI == 3) {
        float* out = (float*)out_;
#pragma unroll
        for (int n = 0; n < 4; ++n) {
          int col = (int)tN + wn * 64 + n * 16 + (lane & 15);
          size_t oi = (size_t)row * N + col;
          out[oi] = res[oi] + acc[m][n][r] + bias[col];
        }
      } else {
        u16* out = (u16*)out_;
#pragma unroll
        for (int n = 0; n < 4; ++n) {
          int col = (int)tN + wn * 64 + n * 16 + (lane & 15);
          float vv = acc[m][n][r] + bias[col];
          if constexpr (EPI == 0) vv *= alpha;
          else vv = 0.5f * vv * (1.f + erff(vv * 0.70710678118654752f));
          out[(size_t)row * N + col] = f2bf(vv);
        }
      }
    }
  }
}

// ------------------------------------------------------------- attention ----
// one wave per (window, head); 8192 units total
__global__ __launch_bounds__(256)
void attn_k(const u16* __restrict__ q, const u16* __restrict__ k,
            const u16* __restrict__ v, const float* __restrict__ rel,
            const float* __restrict__ mask, u16* __restrict__ out) {
  __shared__ u16 kl[4][49 * 32];
  __shared__ u16 vl[4][49 * 32];
  __shared__ float rl[4][169];
  const int w = threadIdx.x >> 6, lane = threadIdx.x & 63;
  const int unit = blockIdx.x * 4 + w;
  const int win = unit >> 3, head = unit & 7;

  for (int gidx = lane; gidx < 196; gidx += 64) {
    int i = gidx >> 2, p = gidx & 3;
    size_t off = ((size_t)win * 49 + i) * 256 + head * 32 + p * 8;
    *(uint4*)&kl[w][i * 32 + p * 8] = *(const uint4*)(k + off);
    *(uint4*)&vl[w][i * 32 + p * 8] = *(const uint4*)(v + off);
  }
  for (int gidx = lane; gidx < 169; gidx += 64) rl[w][gidx] = rel[gidx * 8 + head];
  __syncthreads();

  if (lane < 49) {
    const int i = lane;
    float qr[32];
    {
      const uint4* qp = (const uint4*)(q + ((size_t)win * 49 + i) * 256 + head * 32);
#pragma unroll
      for (int p = 0; p < 4; ++p) {
        uint4 qv = qp[p];
        qr[p * 8 + 0] = bf_lo(qv.x); qr[p * 8 + 1] = bf_hi(qv.x);
        qr[p * 8 + 2] = bf_lo(qv.y); qr[p * 8 + 3] = bf_hi(qv.y);
        qr[p * 8 + 4] = bf_lo(qv.z); qr[p * 8 + 5] = bf_hi(qv.z);
        qr[p * 8 + 6] = bf_lo(qv.w); qr[p * 8 + 7] = bf_hi(qv.w);
      }
    }
    const int ih = i / 7, iw = i - ih * 7;
    const int rbase = ih * 13 + iw;
    const float* mrow = mask + ((size_t)(win & 63) * 49 + i) * 49;
    float sarr[49];
    float mx = -1e30f;
#pragma unroll
    for (int j = 0; j < 49; ++j) {
      const int jh = j / 7, jw = j - jh * 7;
      float a = 0.f;
      const uint4* kp = (const uint4*)&kl[w][j * 32];
#pragma unroll
      for (int p = 0; p < 4; ++p) {
        uint4 kv = kp[p];
        a += qr[p * 8 + 0] * bf_lo(kv.x); a += qr[p * 8 + 1] * bf_hi(kv.x);
        a += qr[p * 8 + 2] * bf_lo(kv.y); a += qr[p * 8 + 3] * bf_hi(kv.y);
        a += qr[p * 8 + 4] * bf_lo(kv.z); a += qr[p * 8 + 5] * bf_hi(kv.z);
        a += qr[p * 8 + 6] * bf_lo(kv.w); a += qr[p * 8 + 7] * bf_hi(kv.w);
      }
      a += rl[w][rbase + (6 - jh) * 13 + (6 - jw)];
      a += mrow[j];
      sarr[j] = a;
      mx = fmaxf(mx, a);
    }
    float sum = 0.f;
#pragma unroll
    for (int j = 0; j < 49; ++j) {
      float e = __expf(sarr[j] - mx);
      sarr[j] = e;
      sum += e;
    }
    float rinv = 1.f / sum;
    float o[32];
#pragma unroll
    for (int d = 0; d < 32; ++d) o[d] = 0.f;
#pragma unroll
    for (int j = 0; j < 49; ++j) {
      float p = sarr[j];
      const uint4* vp = (const uint4*)&vl[w][j * 32];
#pragma unroll
      for (int pp = 0; pp < 4; ++pp) {
        uint4 vv = vp[pp];
        o[pp * 8 + 0] += p * bf_lo(vv.x); o[pp * 8 + 1] += p * bf_hi(vv.x);
        o[pp * 8 + 2] += p * bf_lo(vv.y); o[pp * 8 + 3] += p * bf_hi(vv.y);
        o[pp * 8 + 4] += p * bf_lo(vv.z); o[pp * 8 + 5] += p * bf_hi(vv.z);
        o[pp * 8 + 6] += p * bf_lo(vv.w); o[pp * 8 + 7] += p * bf_hi(vv.w);
      }
    }
    uint4* op = (uint4*)(out + ((size_t)win * 49 + i) * 256 + head * 32);
#pragma unroll
    for (int p = 0; p < 4; ++p) {
      uint4 ov;
      ov.x = pack2bf(o[p * 8 + 0] * rinv, o[p * 8 + 1] * rinv);
      ov.y = pack2bf(o[p * 8 + 2] * rinv, o[p * 8 + 3] * rinv);
      ov.z = pack2bf(o[p * 8 + 4] * rinv, o[p * 8 + 5] * rinv);
      ov.w = pack2bf(o[p * 8 + 6] * rinv, o[p * 8 + 7] * rinv);
      op[p] = ov;
    }
  }
}

// ---------------------------------------------------------------- launch ----
extern "C" void kernel_launch(void* const* d_in, const int* in_sizes, int n_in,
                              void* d_out, int out_size, void* d_ws, size_t ws_size,
                              hipStream_t stream) {
  const float* x1 = (const float*)d_in[0];
  const float* x2 = (const float*)d_in[1];
  const float* x3 = (const float*)d_in[2];
  const float* amask = (const float*)d_in[3];
  const float* g1 = (const float*)d_in[4];
  const float* bb1 = (const float*)d_in[5];
  const float* wq = (const float*)d_in[6];
  const float* bq = (const float*)d_in[7];
  const float* wk = (const float*)d_in[8];
  const float* bk = (const float*)d_in[9];
  const float* wv = (const float*)d_in[10];
  const float* bv = (const float*)d_in[11];
  const float* rel = (const float*)d_in[12];
  const float* wp = (const float*)d_in[13];
  const float* bp = (const float*)d_in[14];
  const float* g2 = (const float*)d_in[15];
  const float* bb2 = (const float*)d_in[16];
  const float* fw1 = (const float*)d_in[17];
  const float* fb1 = (const float*)d_in[18];
  const float* fw2 = (const float*)d_in[19];
  const float* fb2 = (const float*)d_in[20];

  char* wsb = (char*)d_ws;
  const size_t S = (size_t)50176 * 256 * 2;  // one bf16 token-matrix slot
  u16* xw1 = (u16*)(wsb + 0 * S);
  u16* xw2 = (u16*)(wsb + 1 * S);
  u16* xw3 = (u16*)(wsb + 2 * S);
  u16* qb = (u16*)(wsb + 3 * S);
  u16* kbuf = (u16*)(wsb + 4 * S);
  u16* vbuf = (u16*)(wsb + 5 * S);
  u16* attn_o = xw1;                    // reuse slot 0 (xw1 dead after QKV)
  float* x_mid = (float*)(wsb + 1 * S); // slots 1-2 (xw2/xw3 dead)
  u16* x_ln2 = (u16*)(wsb + 3 * S);     // slot 3 (q dead after attn)
  u16* wqt = (u16*)(wsb + 6 * S);
  u16* wkt = wqt + 65536;
  u16* wvt = wkt + 65536;
  u16* wpt = wvt + 65536;
  u16* fw1t = wpt + 65536;
  u16* fw2t = fw1t + 262144;
  u16* h1 = fw2t + 262144;  // 50176 x 1024 bf16

  tconv<<<dim3(256), 256, 0, stream>>>(wq, wqt, 256, 256);
  tconv<<<dim3(256), 256, 0, stream>>>(wk, wkt, 256, 256);
  tconv<<<dim3(256), 256, 0, stream>>>(wv, wvt, 256, 256);
  tconv<<<dim3(256), 256, 0, stream>>>(wp, wpt, 256, 256);
  tconv<<<dim3(1024), 256, 0, stream>>>(fw1, fw1t, 256, 1024);
  tconv<<<dim3(1024), 256, 0, stream>>>(fw2, fw2t, 1024, 256);

  ln1_win<<<dim3(12544), 256, 0, stream>>>(x1, x2, x3, g1, bb1, xw1, xw2, xw3);

  gemm_nt<0><<<dim3(392, 2), 256, 0, stream>>>(xw1, wqt, bq, 0.17677669529663687f,
                                               50176, 256, 256, qb, nullptr);
  gemm_nt<0><<<dim3(392, 2), 256, 0, stream>>>(xw2, wkt, bk, 1.0f, 50176, 256, 256,
                                               kbuf, nullptr);
  gemm_nt<0><<<dim3(392, 2), 256, 0, stream>>>(xw3, wvt, bv, 1.0f, 50176, 256, 256,
                                               vbuf, nullptr);

  attn_k<<<dim3(2048), 256, 0, stream>>>(qb, kbuf, vbuf, rel, amask, attn_o);

  gemm_nt<2><<<dim3(392, 2), 256, 0, stream>>>(attn_o, wpt, bp, 1.0f, 50176, 256, 256,
                                               x_mid, x1);

  ln2_k<<<dim3(12544), 256, 0, stream>>>(x_mid, g2, bb2, x_ln2);

  gemm_nt<1><<<dim3(392, 8), 256, 0, stream>>>(x_ln2, fw1t, fb1, 1.0f, 50176, 1024, 256,
                                               h1, nullptr);
  gemm_nt<3><<<dim3(392, 2), 256, 0, stream>>>(h1, fw2t, fb2, 1.0f, 50176, 256, 1024,
                                               (float*)d_out, x_mid);
}

// Round 2
// 357.439 us; speedup vs baseline: 1.8119x; 1.8119x over previous
//
#include <hip/hip_runtime.h>

typedef unsigned short u16;
typedef short bf16x8 __attribute__((ext_vector_type(8)));
typedef float f32x4 __attribute__((ext_vector_type(4)));

__device__ __forceinline__ u16 f2bf(float f) {
  union { float f; unsigned u; } x; x.f = f;
  unsigned r = x.u + 0x7FFFu + ((x.u >> 16) & 1u);
  return (u16)(r >> 16);
}

// ---------------------------------------------------------------- weights ---
// out[n*K + k] = bf16(in[k*N + n])   (K x N fp32  ->  N x K bf16)
__global__ void tconv(const float* __restrict__ in, u16* __restrict__ out, int K, int N) {
  int idx = blockIdx.x * 256 + threadIdx.x;
  if (idx >= K * N) return;
  int n = idx / K, k2 = idx - n * K;
  out[idx] = f2bf(in[(size_t)k2 * N + n]);
}

// ------------------------------------------------------- LN1+shift+window ---
__global__ __launch_bounds__(256)
void ln1_win(const float* __restrict__ x1, const float* __restrict__ x2,
             const float* __restrict__ x3, const float* __restrict__ g,
             const float* __restrict__ bb, u16* __restrict__ o1,
             u16* __restrict__ o2, u16* __restrict__ o3) {
  const int t = blockIdx.x * 4 + (threadIdx.x >> 6);
  const int lane = threadIdx.x & 63;
  const int win = t / 49, i = t - win * 49;
  const int b = win >> 6, wi = win & 63;
  const int ih = i / 7, iw = i - ih * 7;
  int h2 = (wi >> 3) * 7 + ih + 3; if (h2 >= 56) h2 -= 56;
  int w2 = (wi & 7) * 7 + iw + 3; if (w2 >= 56) w2 -= 56;
  const size_t src = ((size_t)b * 3136 + (size_t)h2 * 56 + w2) * 256 + lane * 4;
  const size_t dst = (size_t)t * 256 + lane * 4;
  const float4 gv = *(const float4*)(g + lane * 4);
  const float4 bv = *(const float4*)(bb + lane * 4);
  const float* xs[3] = {x1, x2, x3};
  u16* os[3] = {o1, o2, o3};
#pragma unroll
  for (int s = 0; s < 3; ++s) {
    float4 v = *(const float4*)(xs[s] + src);
    float sm = v.x + v.y + v.z + v.w;
    float s2 = v.x * v.x + v.y * v.y + v.z * v.z + v.w * v.w;
#pragma unroll
    for (int off = 32; off > 0; off >>= 1) {
      sm += __shfl_down(sm, off);
      s2 += __shfl_down(s2, off);
    }
    sm = __shfl(sm, 0); s2 = __shfl(s2, 0);
    float mean = sm * (1.f / 256.f);
    float rstd = rsqrtf(s2 * (1.f / 256.f) - mean * mean + 1e-5f);
    ushort4 o;
    o.x = f2bf((v.x - mean) * rstd * gv.x + bv.x);
    o.y = f2bf((v.y - mean) * rstd * gv.y + bv.y);
    o.z = f2bf((v.z - mean) * rstd * gv.z + bv.z);
    o.w = f2bf((v.w - mean) * rstd * gv.w + bv.w);
    *(ushort4*)(os[s] + dst) = o;
  }
}

// ------------------------------------------------------------------- LN2 ----
__global__ __launch_bounds__(256)
void ln2_k(const float* __restrict__ x, const float* __restrict__ g,
           const float* __restrict__ bb, u16* __restrict__ o) {
  const int t = blockIdx.x * 4 + (threadIdx.x >> 6);
  const int lane = threadIdx.x & 63;
  const size_t off = (size_t)t * 256 + lane * 4;
  const float4 gv = *(const float4*)(g + lane * 4);
  const float4 bv = *(const float4*)(bb + lane * 4);
  float4 v = *(const float4*)(x + off);
  float sm = v.x + v.y + v.z + v.w;
  float s2 = v.x * v.x + v.y * v.y + v.z * v.z + v.w * v.w;
#pragma unroll
  for (int d = 32; d > 0; d >>= 1) {
    sm += __shfl_down(sm, d);
    s2 += __shfl_down(s2, d);
  }
  sm = __shfl(sm, 0); s2 = __shfl(s2, 0);
  float mean = sm * (1.f / 256.f);
  float rstd = rsqrtf(s2 * (1.f / 256.f) - mean * mean + 1e-5f);
  ushort4 ov;
  ov.x = f2bf((v.x - mean) * rstd * gv.x + bv.x);
  ov.y = f2bf((v.y - mean) * rstd * gv.y + bv.y);
  ov.z = f2bf((v.z - mean) * rstd * gv.z + bv.z);
  ov.w = f2bf((v.w - mean) * rstd * gv.w + bv.w);
  *(ushort4*)(o + off) = ov;
}

// ------------------------------------------------------------------ GEMM ----
#define BM 128
#define BN 128
#define BK 64

template <int EPI>
__global__ __launch_bounds__(256, 2)
void gemm_nt(const u16* __restrict__ A, const u16* __restrict__ Bt,
             const float* __restrict__ bias, float alpha, int M, int N, int K,
             void* __restrict__ out_, const float* __restrict__ res) {
  __shared__ u16 As[2][BM * BK];
  __shared__ u16 Bs[2][BN * BK];
  const int tid = threadIdx.x;
  const int lane = tid & 63;
  const int wave = tid >> 6;
  const int wm = wave >> 1, wn = wave & 1;
  const long tM = (long)blockIdx.x * BM, tN = (long)blockIdx.y * BN;

  f32x4 acc[4][4] = {};

  auto stage = [&](u16* dst, const u16* src, long rowBase, int ld, int kOff) {
#pragma unroll
    for (int it = 0; it < 4; ++it) {
      int gi = it * 256 + tid;
      int row = gi >> 3, gl = gi & 7;
      int gs = gl ^ (row & 7);
      uint4 vv = *(const uint4*)(src + (size_t)(rowBase + row) * ld + kOff + gs * 8);
      *(uint4*)(dst + row * BK + gl * 8) = vv;
    }
  };

  stage(As[0], A, tM, K, 0);
  stage(Bs[0], Bt, tN, K, 0);
  __syncthreads();

  const int nkt = K / BK;
  for (int kt = 0; kt < nkt; ++kt) {
    const int cur = kt & 1;
    if (kt + 1 < nkt) {
      stage(As[cur ^ 1], A, tM, K, (kt + 1) * BK);
      stage(Bs[cur ^ 1], Bt, tN, K, (kt + 1) * BK);
    }
#pragma unroll
    for (int kk = 0; kk < BK; kk += 32) {
      bf16x8 af[4], bfv[4];
#pragma unroll
      for (int m = 0; m < 4; ++m) {
        int row = wm * 64 + m * 16 + (lane & 15);
        int g = (kk >> 3) + (lane >> 4);
        af[m] = *(const bf16x8*)&As[cur][row * BK + ((g ^ (row & 7)) << 3)];
      }
#pragma unroll
      for (int n = 0; n < 4; ++n) {
        int col = wn * 64 + n * 16 + (lane & 15);
        int g = (kk >> 3) + (lane >> 4);
        bfv[n] = *(const bf16x8*)&Bs[cur][col * BK + ((g ^ (col & 7)) << 3)];
      }
#pragma unroll
      for (int m = 0; m < 4; ++m)
#pragma unroll
        for (int n = 0; n < 4; ++n)
          acc[m][n] = __builtin_amdgcn_mfma_f32_16x16x32_bf16(af[m], bfv[n], acc[m][n], 0, 0, 0);
    }
    __syncthreads();
  }

#pragma unroll
  for (int m = 0; m < 4; ++m) {
#pragma unroll
    for (int r = 0; r < 4; ++r) {
      const long row = tM + wm * 64 + m * 16 + (lane >> 4) * 4 + r;
      if constexpr (EPI == 2) {
        int win = (int)(row / 49), i = (int)(row - (long)win * 49);
        int b = win >> 6, wi = win & 63;
        int ih = i / 7, iw = i - ih * 7;
        int h2 = (wi >> 3) * 7 + ih + 3; if (h2 >= 56) h2 -= 56;
        int w2 = (wi & 7) * 7 + iw + 3; if (w2 >= 56) w2 -= 56;
        size_t obase = ((size_t)b * 3136 + (size_t)h2 * 56 + w2) * 256;
        float* out = (float*)out_;
#pragma unroll
        for (int n = 0; n < 4; ++n) {
          int col = (int)tN + wn * 64 + n * 16 + (lane & 15);
          out[obase + col] = res[obase + col] + acc[m][n][r] + bias[col];
        }
      } else if constexpr (EPI == 3) {
        float* out = (float*)out_;
#pragma unroll
        for (int n = 0; n < 4; ++n) {
          int col = (int)tN + wn * 64 + n * 16 + (lane & 15);
          size_t oi = (size_t)row * N + col;
          out[oi] = res[oi] + acc[m][n][r] + bias[col];
        }
      } else {
        u16* out = (u16*)out_;
#pragma unroll
        for (int n = 0; n < 4; ++n) {
          int col = (int)tN + wn * 64 + n * 16 + (lane & 15);
          float vv = acc[m][n][r] + bias[col];
          if constexpr (EPI == 0) vv *= alpha;
          else vv = 0.5f * vv * (1.f + erff(vv * 0.70710678118654752f));
          out[(size_t)row * N + col] = f2bf(vv);
        }
      }
    }
  }
}

// ------------------------------------------------- combined attn bias prep --
// Bp[(wi*8+h)*4096 + ((mi*4+ni)*64 + lane)*4 + r] = bias for MFMA C-layout
// position (row = mi*16+(lane>>4)*4+r, col = ni*16+(lane&15)).
__global__ __launch_bounds__(256)
void bias_prep(const float* __restrict__ rel, const float* __restrict__ mask,
               float* __restrict__ Bp) {
  const int blk = blockIdx.x;  // 0..511
  const int wi = blk >> 3, h = blk & 7;
  const float* mrow = mask + (size_t)wi * 2401;
  float* o = Bp + (size_t)blk * 4096;
#pragma unroll
  for (int e = 0; e < 16; ++e) {
    int pos = e * 256 + threadIdx.x;
    int r = pos & 3, lane = (pos >> 2) & 63, mini = pos >> 8;
    int mi = mini >> 2, ni = mini & 3;
    int row = mi * 16 + (lane >> 4) * 4 + r;
    int col = ni * 16 + (lane & 15);
    float val;
    if (col >= 49) val = -1e30f;
    else if (row >= 49) val = 0.f;
    else {
      int idx = (row / 7 - col / 7 + 6) * 13 + (row % 7 - col % 7 + 6);
      val = rel[idx * 8 + h] + mrow[row * 49 + col];
    }
    o[pos] = val;
  }
}

// ------------------------------------------------------- MFMA attention -----
// one 64-thread block per (window, head); 8192 blocks.
// S = Q K^T (64x64 padded, acc-init = combined bias), wave-parallel softmax,
// P and V^T through XOR-swizzled LDS, O = P V via MFMA.
__global__ __launch_bounds__(64)
void attn_mfma(const u16* __restrict__ q, const u16* __restrict__ k,
               const u16* __restrict__ v, const float* __restrict__ Bp,
               u16* __restrict__ out) {
  __shared__ u16 Pl[64 * 64];
  __shared__ u16 VT[32 * 64];
  const int lane = threadIdx.x;
  const int unit = blockIdx.x;
  const int win = unit >> 3, head = unit & 7;
  const size_t base = (size_t)win * 49 * 256 + head * 32;

  // --- stage V^T (swizzled); zero cols (keys) >= 49 to avoid NaN*0 ---
  {
    const int key = lane;
    const u16* vp = v + base + (size_t)key * 256;
#pragma unroll
    for (int p = 0; p < 4; ++p) {
      bf16x8 vv = {};
      if (key < 49) vv = *(const bf16x8*)(vp + p * 8);
#pragma unroll
      for (int e = 0; e < 8; ++e) {
        int dim = p * 8 + e;
        int sw = (dim ^ (dim >> 3)) & 7;
        VT[dim * 64 + ((((key >> 3) ^ sw) << 3) | (key & 7))] = (u16)vv[e];
      }
    }
  }

  // --- acc init = bias (pre-laid-out in MFMA C order) ---
  const f32x4* bp = (const f32x4*)(Bp + (size_t)((win & 63) * 8 + head) * 4096);
  f32x4 acc[4][4];
#pragma unroll
  for (int mi = 0; mi < 4; ++mi)
#pragma unroll
    for (int ni = 0; ni < 4; ++ni)
      acc[mi][ni] = bp[(mi * 4 + ni) * 64 + lane];

  // --- Q/K fragments straight from global (A: m=lane&15, k=(lane>>4)*8+j) ---
  bf16x8 qf[4], kf[4];
#pragma unroll
  for (int mi = 0; mi < 4; ++mi)
    qf[mi] = *(const bf16x8*)(q + base + (size_t)(mi * 16 + (lane & 15)) * 256 + (lane >> 4) * 8);
#pragma unroll
  for (int ni = 0; ni < 4; ++ni)
    kf[ni] = *(const bf16x8*)(k + base + (size_t)(ni * 16 + (lane & 15)) * 256 + (lane >> 4) * 8);

#pragma unroll
  for (int mi = 0; mi < 4; ++mi)
#pragma unroll
    for (int ni = 0; ni < 4; ++ni)
      acc[mi][ni] = __builtin_amdgcn_mfma_f32_16x16x32_bf16(qf[mi], kf[ni], acc[mi][ni], 0, 0, 0);

  // --- wave-parallel softmax: row = (mi,r) local; cols = 4 ni x 16 lanes ---
  float rinv[4][4];
#pragma unroll
  for (int mi = 0; mi < 4; ++mi) {
#pragma unroll
    for (int r = 0; r < 4; ++r) {
      float mx = fmaxf(fmaxf(acc[mi][0][r], acc[mi][1][r]),
                       fmaxf(acc[mi][2][r], acc[mi][3][r]));
#pragma unroll
      for (int off = 1; off < 16; off <<= 1) mx = fmaxf(mx, __shfl_xor(mx, off));
      float s = 0.f;
#pragma unroll
      for (int ni = 0; ni < 4; ++ni) {
        float e = __expf(acc[mi][ni][r] - mx);
        acc[mi][ni][r] = e;
        s += e;
      }
#pragma unroll
      for (int off = 1; off < 16; off <<= 1) s += __shfl_xor(s, off);
      rinv[mi][r] = 1.f / s;
    }
  }

  // --- P -> LDS bf16 (swizzled scatter; all 64x64 written, pad cols = 0) ---
#pragma unroll
  for (int mi = 0; mi < 4; ++mi)
#pragma unroll
    for (int ni = 0; ni < 4; ++ni)
#pragma unroll
      for (int r = 0; r < 4; ++r) {
        int row = mi * 16 + (lane >> 4) * 4 + r;
        int col = ni * 16 + (lane & 15);
        int sw = (row ^ (row >> 3)) & 7;
        Pl[row * 64 + ((((col >> 3) ^ sw) << 3) | (col & 7))] = f2bf(acc[mi][ni][r]);
      }

  // --- O = P V ---
  f32x4 acc2[4][2] = {};
#pragma unroll
  for (int ks = 0; ks < 2; ++ks) {
    bf16x8 pa[4], vb[2];
#pragma unroll
    for (int mi = 0; mi < 4; ++mi) {
      int row = mi * 16 + (lane & 15);
      int sw = (row ^ (row >> 3)) & 7;
      pa[mi] = *(const bf16x8*)&Pl[row * 64 + (((ks * 4 + (lane >> 4)) ^ sw) << 3)];
    }
#pragma unroll
    for (int n2 = 0; n2 < 2; ++n2) {
      int dim = n2 * 16 + (lane & 15);
      int sw = (dim ^ (dim >> 3)) & 7;
      vb[n2] = *(const bf16x8*)&VT[dim * 64 + (((ks * 4 + (lane >> 4)) ^ sw) << 3)];
    }
#pragma unroll
    for (int mi = 0; mi < 4; ++mi)
#pragma unroll
      for (int n2 = 0; n2 < 2; ++n2)
        acc2[mi][n2] = __builtin_amdgcn_mfma_f32_16x16x32_bf16(pa[mi], vb[n2], acc2[mi][n2], 0, 0, 0);
  }

  // --- store (apply 1/rowsum; rows >= 49 discarded) ---
#pragma unroll
  for (int mi = 0; mi < 4; ++mi)
#pragma unroll
    for (int r = 0; r < 4; ++r) {
      int row = mi * 16 + (lane >> 4) * 4 + r;
      if (row < 49) {
        float rv = rinv[mi][r];
#pragma unroll
        for (int n2 = 0; n2 < 2; ++n2) {
          int col = n2 * 16 + (lane & 15);
          out[base + (size_t)row * 256 + col] = f2bf(acc2[mi][n2][r] * rv);
        }
      }
    }
}

// ---------------------------------------------------------------- launch ----
extern "C" void kernel_launch(void* const* d_in, const int* in_sizes, int n_in,
                              void* d_out, int out_size, void* d_ws, size_t ws_size,
                              hipStream_t stream) {
  const float* x1 = (const float*)d_in[0];
  const float* x2 = (const float*)d_in[1];
  const float* x3 = (const float*)d_in[2];
  const float* amask = (const float*)d_in[3];
  const float* g1 = (const float*)d_in[4];
  const float* bb1 = (const float*)d_in[5];
  const float* wq = (const float*)d_in[6];
  const float* bq = (const float*)d_in[7];
  const float* wk = (const float*)d_in[8];
  const float* bk = (const float*)d_in[9];
  const float* wv = (const float*)d_in[10];
  const float* bv = (const float*)d_in[11];
  const float* rel = (const float*)d_in[12];
  const float* wp = (const float*)d_in[13];
  const float* bp = (const float*)d_in[14];
  const float* g2 = (const float*)d_in[15];
  const float* bb2 = (const float*)d_in[16];
  const float* fw1 = (const float*)d_in[17];
  const float* fb1 = (const float*)d_in[18];
  const float* fw2 = (const float*)d_in[19];
  const float* fb2 = (const float*)d_in[20];

  char* wsb = (char*)d_ws;
  const size_t S = (size_t)50176 * 256 * 2;  // one bf16 token-matrix slot
  u16* xw1 = (u16*)(wsb + 0 * S);
  u16* xw2 = (u16*)(wsb + 1 * S);
  u16* xw3 = (u16*)(wsb + 2 * S);
  u16* qb = (u16*)(wsb + 3 * S);
  u16* kbuf = (u16*)(wsb + 4 * S);
  u16* vbuf = (u16*)(wsb + 5 * S);
  u16* attn_o = xw1;                    // reuse slot 0 (xw1 dead after QKV)
  float* x_mid = (float*)(wsb + 1 * S); // slots 1-2 (xw2/xw3 dead)
  u16* x_ln2 = (u16*)(wsb + 3 * S);     // slot 3 (q dead after attn)
  u16* wqt = (u16*)(wsb + 6 * S);
  u16* wkt = wqt + 65536;
  u16* wvt = wkt + 65536;
  u16* wpt = wvt + 65536;
  u16* fw1t = wpt + 65536;
  u16* fw2t = fw1t + 262144;
  u16* h1 = fw2t + 262144;      // 50176 x 1024 bf16 (used only by MLP)
  float* Bp = (float*)h1;       // attn bias table: lifetime disjoint from h1

  bias_prep<<<dim3(512), 256, 0, stream>>>(rel, amask, Bp);

  tconv<<<dim3(256), 256, 0, stream>>>(wq, wqt, 256, 256);
  tconv<<<dim3(256), 256, 0, stream>>>(wk, wkt, 256, 256);
  tconv<<<dim3(256), 256, 0, stream>>>(wv, wvt, 256, 256);
  tconv<<<dim3(256), 256, 0, stream>>>(wp, wpt, 256, 256);
  tconv<<<dim3(1024), 256, 0, stream>>>(fw1, fw1t, 256, 1024);
  tconv<<<dim3(1024), 256, 0, stream>>>(fw2, fw2t, 1024, 256);

  ln1_win<<<dim3(12544), 256, 0, stream>>>(x1, x2, x3, g1, bb1, xw1, xw2, xw3);

  gemm_nt<0><<<dim3(392, 2), 256, 0, stream>>>(xw1, wqt, bq, 0.17677669529663687f,
                                               50176, 256, 256, qb, nullptr);
  gemm_nt<0><<<dim3(392, 2), 256, 0, stream>>>(xw2, wkt, bk, 1.0f, 50176, 256, 256,
                                               kbuf, nullptr);
  gemm_nt<0><<<dim3(392, 2), 256, 0, stream>>>(xw3, wvt, bv, 1.0f, 50176, 256, 256,
                                               vbuf, nullptr);

  attn_mfma<<<dim3(8192), 64, 0, stream>>>(qb, kbuf, vbuf, Bp, attn_o);

  gemm_nt<2><<<dim3(392, 2), 256, 0, stream>>>(attn_o, wpt, bp, 1.0f, 50176, 256, 256,
                                               x_mid, x1);

  ln2_k<<<dim3(12544), 256, 0, stream>>>(x_mid, g2, bb2, x_ln2);

  gemm_nt<1><<<dim3(392, 8), 256, 0, stream>>>(x_ln2, fw1t, fb1, 1.0f, 50176, 1024, 256,
                                               h1, nullptr);
  gemm_nt<3><<<dim3(392, 2), 256, 0, stream>>>(h1, fw2t, fb2, 1.0f, 50176, 256, 1024,
                                               (float*)d_out, x_mid);
}